// Round 3
// baseline (123.604 us; speedup 1.0000x reference)
//
#include <hip/hip_runtime.h>
#include <hip/hip_bf16.h>
#include <math.h>

typedef __attribute__((ext_vector_type(8))) short short8;
typedef __attribute__((ext_vector_type(4))) float f32x4;

#define T_SEQ 2048
#define NVOC 42

// ws float offsets
#define OFF_TAU 0        // 42*43 = 1806 f32
#define OFF_WB  1808     // u16 region: 12288 u16 ([8 n][16 col][96 k] bf16) = 6144 f32 -> 7952
#define OFF_HB  7952     // u16 region: 6144 u16 ([12 frag][64 lane][8] bf16) = 3072 f32 -> 11024

static __device__ __forceinline__ short f2b(float x){
  __hip_bfloat16 h = __float2bfloat16(x);
  return *reinterpret_cast<short*>(&h);
}

// Single fused precompute kernel, 128 blocks x 256 threads, block-local deps only.
//  blocks 0..41   : tau row a (recomputes ue[a] + full re locally; silu-dot; sigmoid)
//  blocks 42..84  : c -> ve[c] (LDS) -> vm[c] -> wb bf16 column k=c
//  blocks 85..126 : a -> ya[a] -> wb bf16 column k=43+a
//  block 127      : head_w B-frag pack + zero wb k=85..95
__global__ __launch_bounds__(256) void k_pre(const float* __restrict__ emb,
    const float* __restrict__ w1, const float* __restrict__ b1,
    const float* __restrict__ w2, const float* __restrict__ b2,
    const float* __restrict__ wv_w, const float* __restrict__ wv_b,
    const float* __restrict__ mg_w, const float* __restrict__ mg_b,
    const float* __restrict__ head_w, float* __restrict__ ws){
  __shared__ float sm[8192];
  int blk = blockIdx.x, tid = threadIdx.x;
  ushort* wbu = (ushort*)(ws + OFF_WB);
  if (blk < 42){
    int a = blk;
    // stage all 42 emb rows (5376 f32) to LDS, coalesced
    {
      float4* d4 = (float4*)sm;
      const float4* e4 = (const float4*)emb;
      for (int i = tid; i < 1344; i += 256) d4[i] = e4[i];
    }
    __syncthreads();
    float* s_emb = sm;            // 5376
    float* s_ue  = sm + 5376;     // 64
    float* s_sil = sm + 5440;     // 2752
    if (tid < 64){
      float su = b1[tid];
      const float* er = s_emb + a*128;
      for (int i = 0; i < 128; ++i) su = fmaf(er[i], w1[i*64 + tid], su);
      s_ue[tid] = su;
    }
    __syncthreads();
    for (int p = tid; p < 2752; p += 256){
      int c = p >> 6, k = p & 63;             // c uniform per wave; k = lane&63 -> coalesced w1
      float re = 0.f;
      if (c < 42){
        const float* er = s_emb + c*128;
        for (int i = 0; i < 128; i += 4){
          float4 ev = *(const float4*)(er + i);
          re = fmaf(ev.x, w1[(128+i)*64 + k], re);
          re = fmaf(ev.y, w1[(129+i)*64 + k], re);
          re = fmaf(ev.z, w1[(130+i)*64 + k], re);
          re = fmaf(ev.w, w1[(131+i)*64 + k], re);
        }
      }
      float h = s_ue[k] + re;
      float sg = 1.f/(1.f + __expf(-h));
      s_sil[p] = h * sg * w2[k];
    }
    __syncthreads();
    if (tid < 43){
      float s = b2[0];
      const float* sp = s_sil + tid*64;
      for (int k = 0; k < 64; ++k) s += sp[k];
      ws[OFF_TAU + a*43 + tid] = 1.f/(1.f + __expf(-s));
    }
  } else if (blk < 85){
    int c = blk - 42;                          // 0..42 (42 == zero-padded neighbor)
    float* s_ve = sm;
    if (tid < 128){
      float v = wv_b[tid];
      if (c < 42){
        for (int i = 0; i < 128; ++i) v = fmaf(emb[c*128 + i], wv_w[i*128 + tid], v);
      }
      s_ve[tid] = v;
    }
    __syncthreads();
    if (tid < 128){
      int d = tid; float s = 0.f;
      for (int i = 0; i < 128; ++i) s = fmaf(s_ve[i], mg_w[(128+i)*128 + d], s);
      wbu[(d>>4)*1536 + (d&15)*96 + c] = (ushort)f2b(s);
    }
  } else if (blk < 127){
    int a = blk - 85;
    if (tid < 128){
      int d = tid; float s = mg_b[d];
      for (int i = 0; i < 128; ++i) s = fmaf(emb[a*128 + i], mg_w[i*128 + d], s);
      wbu[(d>>4)*1536 + (d&15)*96 + (43+a)] = (ushort)f2b(s);
    }
  } else {
    ushort* hbu = (ushort*)(ws + OFF_HB);
    for (int i2 = tid; i2 < 6144; i2 += 256){
      int f = i2 >> 9, ln = (i2 >> 3) & 63, j = i2 & 7;
      int n2 = f >> 2, cc = f & 3;
      int k = cc*32 + (ln>>4)*8 + j;
      int col = n2*16 + (ln & 15);
      float v = (col < NVOC) ? head_w[k*NVOC + col] : 0.f;
      hbu[i2] = (ushort)f2b(v);
    }
    for (int i = tid; i < 1408; i += 256){
      int n = i/176, rem = i%176, col = rem/11, k = 85 + rem%11;
      wbu[n*1536 + col*96 + k] = 0;
    }
  }
}

// Main: per wave 16 tokens. wb staged to LDS (only table staged); tau gathered from
// global per-lane; T built wave-locally (overlaps staging); ONE barrier; 2 MFMA stages.
__global__ __launch_bounds__(256) void k_main(const int* __restrict__ ids,
    const float* __restrict__ ln_g, const float* __restrict__ ln_b,
    const float* __restrict__ head_b, const float* __restrict__ ws,
    float* __restrict__ out){
  __shared__ __align__(16) ushort s_wb[12288];
  __shared__ __align__(16) float  s_T[4][1600];   // per-wave: T[16][100] f32, later Y[16][136] bf16
  __shared__ int s_ids[4][32];

  int tid = threadIdx.x, wv = tid >> 6, lane = tid & 63;
  int r = lane & 15, q = lane >> 4;
  int base = blockIdx.x*64 + wv*16;

  // stage wb: 6 x float4 per thread (coalesced, balanced banks)
  {
    const float4* s2 = (const float4*)(ws + OFF_WB);
    float4* d2 = (float4*)s_wb;
    #pragma unroll
    for (int jj = 0; jj < 6; ++jj){ int i = tid + jj*256; d2[i] = s2[i]; }
  }
  // per-wave ids (wave-local LDS; wave-coherent, no barrier needed)
  if (lane < 32){
    int v;
    if ((base & (T_SEQ-1)) == 0 && lane < 16) v = NVOC;   // pad before sequence start
    else v = ids[base - 16 + lane];
    s_ids[wv][lane] = v;
  }
  // resident head B-frags + LN params + head bias
  short8 HBf[3][4];
  {
    const ushort* hbsrc = (const ushort*)(ws + OFF_HB);
    #pragma unroll
    for (int n2 = 0; n2 < 3; ++n2)
      #pragma unroll
      for (int c = 0; c < 4; ++c)
        HBf[n2][c] = *(const short8*)&hbsrc[((n2*4 + c)*64 + lane)*8];
  }
  float gd[8], bd[8];
  #pragma unroll
  for (int n = 0; n < 8; ++n){ gd[n] = ln_g[n*16 + r]; bd[n] = ln_b[n*16 + r]; }
  float hb[3];
  #pragma unroll
  for (int n2 = 0; n2 < 3; ++n2){ int col = n2*16 + r; hb[n2] = (col < NVOC) ? head_b[col] : 0.f; }

  // zero this wave's T region (400 float4)
  float* T = s_T[wv];
  {
    float4 z; z.x = z.y = z.z = z.w = 0.f;
    float4* t4 = (float4*)T;
    #pragma unroll
    for (int i = 0; i < 7; ++i){ int idx = lane + i*64; if (idx < 400) t4[idx] = z; }
  }
  // build T: tau gathered straight from global (L2-hot), ds_add into wave-local T
  int a = s_ids[wv][16 + r];
  const float* tau_g = ws + OFF_TAU;
  #pragma unroll
  for (int m = 0; m < 4; ++m){
    int w = q*4 + m;
    int c = s_ids[wv][r + 15 - w];
    float tv = tau_g[a*43 + c];
    atomicAdd(&T[r*100 + c], tv);
  }
  if (q == 0) T[r*100 + 43 + a] = 1.0f;          // selects ya row
  __asm__ volatile("s_waitcnt lgkmcnt(0)" ::: "memory");

  // A-frags for msg MFMA (wave-local, before the barrier)
  short8 A1[3];
  #pragma unroll
  for (int ct = 0; ct < 3; ++ct){
    const float4* p = (const float4*)&T[r*100 + ct*32 + q*8];
    float4 u0 = p[0], u1 = p[1];
    short8 v;
    v[0]=f2b(u0.x); v[1]=f2b(u0.y); v[2]=f2b(u0.z); v[3]=f2b(u0.w);
    v[4]=f2b(u1.x); v[5]=f2b(u1.y); v[6]=f2b(u1.z); v[7]=f2b(u1.w);
    A1[ct] = v;
  }
  __syncthreads();                               // wb staged by all waves

  // msg+ya MFMA: y[16 tok x 128 d] = T[16x96] @ W[96x128]
  f32x4 accm[8];
  #pragma unroll
  for (int n = 0; n < 8; ++n){ accm[n][0]=0.f; accm[n][1]=0.f; accm[n][2]=0.f; accm[n][3]=0.f; }
  #pragma unroll
  for (int ct = 0; ct < 3; ++ct){
    #pragma unroll
    for (int n = 0; n < 8; ++n){
      short8 b = *(const short8*)&s_wb[n*1536 + r*96 + ct*32 + q*8];
      accm[n] = __builtin_amdgcn_mfma_f32_16x16x32_bf16(A1[ct], b, accm[n], 0, 0, 0);
    }
  }

  // LN + cyclic scale, write Y bf16 to wave-local LDS (overlay on T)
  ushort* sY = (ushort*)T;                       // Y[16][136] bf16
  #pragma unroll
  for (int reg = 0; reg < 4; ++reg){
    float s1 = 0.f, s2 = 0.f;
    #pragma unroll
    for (int n = 0; n < 8; ++n){ float y = accm[n][reg]; s1 += y; s2 = fmaf(y, y, s2); }
    #pragma unroll
    for (int mk = 1; mk < 16; mk <<= 1){ s1 += __shfl_xor(s1, mk); s2 += __shfl_xor(s2, mk); }
    float mu  = s1 * (1.f/128.f);
    float var = s2 * (1.f/128.f) - mu*mu;
    float rinv = rsqrtf(var + 1e-5f);
    int tok = base + q*4 + reg;
    int m12 = ((tok & (T_SEQ-1)) + 8) % 12;      // (btt + 2048) mod 12
    float sc = fmaf(0.15f, __sinf((float)m12 * 0.52359877559829887f), 1.0f);
    float A_ = rinv * sc;
    #pragma unroll
    for (int n = 0; n < 8; ++n){
      float yl = (accm[n][reg] - mu) * A_;
      float o  = fmaf(yl, gd[n], bd[n]*sc);
      sY[(q*4 + reg)*136 + n*16 + r] = (ushort)f2b(o);
    }
  }

  // head MFMA: out[16 tok x 48] = Y[16x128] @ HW[128x48] (wave-local reads, no barrier)
  f32x4 acch[3];
  #pragma unroll
  for (int n2 = 0; n2 < 3; ++n2){ acch[n2][0]=0.f; acch[n2][1]=0.f; acch[n2][2]=0.f; acch[n2][3]=0.f; }
  short8 A2[4];
  #pragma unroll
  for (int c = 0; c < 4; ++c)
    A2[c] = *(const short8*)&sY[r*136 + c*32 + q*8];
  #pragma unroll
  for (int c = 0; c < 4; ++c){
    #pragma unroll
    for (int n2 = 0; n2 < 3; ++n2)
      acch[n2] = __builtin_amdgcn_mfma_f32_16x16x32_bf16(A2[c], HBf[n2][c], acch[n2], 0, 0, 0);
  }
  #pragma unroll
  for (int n2 = 0; n2 < 3; ++n2){
    int col = n2*16 + r;
    if (col < NVOC){
      #pragma unroll
      for (int reg = 0; reg < 4; ++reg){
        int tok = base + q*4 + reg;
        out[tok*NVOC + col] = acch[n2][reg] + hb[n2];
      }
    }
  }
}

extern "C" void kernel_launch(void* const* d_in, const int* in_sizes, int n_in,
                              void* d_out, int out_size, void* d_ws, size_t ws_size,
                              hipStream_t stream){
  const int*   ids    = (const int*)  d_in[0];
  const float* emb    = (const float*)d_in[1];
  const float* w1     = (const float*)d_in[2];
  const float* b1     = (const float*)d_in[3];
  const float* w2     = (const float*)d_in[4];
  const float* b2     = (const float*)d_in[5];
  const float* wv_w   = (const float*)d_in[6];
  const float* wv_b   = (const float*)d_in[7];
  const float* mg_w   = (const float*)d_in[8];
  const float* mg_b   = (const float*)d_in[9];
  const float* ln_g   = (const float*)d_in[10];
  const float* ln_b   = (const float*)d_in[11];
  const float* head_w = (const float*)d_in[12];
  const float* head_b = (const float*)d_in[13];
  float* ws  = (float*)d_ws;
  float* out = (float*)d_out;
  k_pre <<<dim3(128), dim3(256), 0, stream>>>(emb, w1, b1, w2, b2, wv_w, wv_b,
                                              mg_w, mg_b, head_w, ws);
  k_main<<<dim3(512), dim3(256), 0, stream>>>(ids, ln_g, ln_b, head_b, ws, out);
}

// Round 4
// 35.543 us; speedup vs baseline: 3.4775x; 3.4775x over previous
//
#include <hip/hip_runtime.h>
#include <hip/hip_bf16.h>
#include <math.h>

typedef __attribute__((ext_vector_type(8))) short short8;
typedef __attribute__((ext_vector_type(4))) float f32x4;

#define T_SEQ 2048
#define NVOC 42

// ws float offsets
#define OFF_TAU 0        // 42*43 = 1806 f32
#define OFF_WB  1808     // u16 region: 12288 u16 ([8 n][16 col][96 k] bf16) = 6144 f32 -> 7952
#define OFF_HB  7952     // u16 region: 6144 u16 ([12 frag][64 lane][8] bf16) = 3072 f32 -> 11024

static __device__ __forceinline__ short f2b(float x){
  __hip_bfloat16 h = __float2bfloat16(x);
  return *reinterpret_cast<short*>(&h);
}

// Fused precompute, 128 blocks x 256 threads, block-local deps only.
//  blocks 0..41   : tau row a. w1 register-cached per 16-row chunk (reused across c),
//                   emb via wave-uniform scalar loads, shfl-reduce. No LDS, no barrier.
//  blocks 42..84  : c -> ve[c] -> vm[c] -> wb bf16 column k=c      (2-way i-split)
//  blocks 85..126 : a -> ya[a] -> wb bf16 column k=43+a            (2-way i-split)
//  block 127      : head_w B-frag pack + zero wb k=85..95
__global__ __launch_bounds__(256) void k_pre(const float* __restrict__ emb,
    const float* __restrict__ w1, const float* __restrict__ b1,
    const float* __restrict__ w2, const float* __restrict__ b2,
    const float* __restrict__ wv_w, const float* __restrict__ wv_b,
    const float* __restrict__ mg_w, const float* __restrict__ mg_b,
    const float* __restrict__ head_w, float* __restrict__ ws){
  int blk = blockIdx.x, tid = threadIdx.x;
  ushort* wbu = (ushort*)(ws + OFF_WB);
  if (blk < 42){
    int a = blk;
    int lane = tid & 63;
    int wvu = __builtin_amdgcn_readfirstlane(tid >> 6);   // wave id, SGPR
    int k = lane;
    float w2k = w2[k];
    float uacc = b1[k];
    float reacc[11];
    #pragma unroll
    for (int cc = 0; cc < 11; ++cc) reacc[cc] = 0.f;
    #pragma unroll
    for (int chunk = 0; chunk < 8; ++chunk){
      // 32 independent coalesced w1 loads for this chunk (registers, reused across c)
      float w1u[16], w1r[16];
      #pragma unroll
      for (int j = 0; j < 16; ++j){
        w1u[j] = w1[(chunk*16 + j)*64 + k];
        w1r[j] = w1[(128 + chunk*16 + j)*64 + k];
      }
      // ue accumulation: emb[a] is uniform (scalar loads)
      {
        const float* ea = emb + a*128 + chunk*16;
        #pragma unroll
        for (int j = 0; j < 16; ++j) uacc = fmaf(ea[j], w1u[j], uacc);
      }
      // re accumulation for this wave's c-set: c = wvu + 4*cc
      #pragma unroll
      for (int cc = 0; cc < 11; ++cc){
        int c = wvu + 4*cc;
        if (c < 42){
          const float* ec = emb + c*128 + chunk*16;
          #pragma unroll
          for (int j = 0; j < 16; ++j) reacc[cc] = fmaf(ec[j], w1r[j], reacc[cc]);
        }
      }
    }
    float b20 = b2[0];
    #pragma unroll
    for (int cc = 0; cc < 11; ++cc){
      int c = wvu + 4*cc;
      if (c < 43){
        float h  = uacc + ((c < 42) ? reacc[cc] : 0.f);
        float sg = 1.f/(1.f + __expf(-h));
        float sl = h * sg * w2k;
        #pragma unroll
        for (int mk = 1; mk < 64; mk <<= 1) sl += __shfl_xor(sl, mk);
        if (lane == 0)
          ws[OFF_TAU + a*43 + c] = 1.f/(1.f + __expf(-(sl + b20)));
      }
    }
  } else if (blk < 85){
    int c = blk - 42;                          // 0..42 (42 == zero-padded neighbor)
    __shared__ float s_p[2][128];
    __shared__ float s_ve[128];
    int d = tid & 127, h = tid >> 7;
    {
      float acc = (h == 0) ? wv_b[d] : 0.f;
      if (c < 42){
        const float* ec = emb + c*128 + h*64;
        const float* wp = wv_w + (h*64)*128 + d;
        #pragma unroll 8
        for (int i = 0; i < 64; ++i) acc = fmaf(ec[i], wp[i*128], acc);
      }
      s_p[h][d] = acc;
    }
    __syncthreads();
    if (h == 0) s_ve[d] = s_p[0][d] + s_p[1][d];
    __syncthreads();
    {
      float acc = 0.f;
      const float* vp = s_ve + h*64;
      const float* mp = mg_w + (128 + h*64)*128 + d;
      #pragma unroll 8
      for (int i = 0; i < 64; ++i) acc = fmaf(vp[i], mp[i*128], acc);
      s_p[h][d] = acc;
    }
    __syncthreads();
    if (h == 0){
      float vm = s_p[0][d] + s_p[1][d];
      wbu[(d>>4)*1536 + (d&15)*96 + c] = (ushort)f2b(vm);
    }
  } else if (blk < 127){
    int a = blk - 85;
    __shared__ float s_p[2][128];
    int d = tid & 127, h = tid >> 7;
    {
      float acc = (h == 0) ? mg_b[d] : 0.f;
      const float* ea = emb + a*128 + h*64;
      const float* mp = mg_w + (h*64)*128 + d;
      #pragma unroll 8
      for (int i = 0; i < 64; ++i) acc = fmaf(ea[i], mp[i*128], acc);
      s_p[h][d] = acc;
    }
    __syncthreads();
    if (h == 0){
      float ya = s_p[0][d] + s_p[1][d];
      wbu[(d>>4)*1536 + (d&15)*96 + (43+a)] = (ushort)f2b(ya);
    }
  } else {
    ushort* hbu = (ushort*)(ws + OFF_HB);
    for (int i2 = tid; i2 < 6144; i2 += 256){
      int f = i2 >> 9, ln = (i2 >> 3) & 63, j = i2 & 7;
      int n2 = f >> 2, cc = f & 3;
      int kk = cc*32 + (ln>>4)*8 + j;
      int col = n2*16 + (ln & 15);
      float v = (col < NVOC) ? head_w[kk*NVOC + col] : 0.f;
      hbu[i2] = (ushort)f2b(v);
    }
    for (int i = tid; i < 1408; i += 256){
      int n = i/176, rem = i%176, col = rem/11, kk = 85 + rem%11;
      wbu[n*1536 + col*96 + kk] = 0;
    }
  }
}

// Main: per wave 16 tokens. wb staged to LDS; tau gathered from global per-lane;
// T built wave-locally (overlaps staging); ONE barrier; 2 MFMA stages.
__global__ __launch_bounds__(256) void k_main(const int* __restrict__ ids,
    const float* __restrict__ ln_g, const float* __restrict__ ln_b,
    const float* __restrict__ head_b, const float* __restrict__ ws,
    float* __restrict__ out){
  __shared__ __align__(16) ushort s_wb[12288];
  __shared__ __align__(16) float  s_T[4][1600];   // per-wave: T[16][100] f32, later Y[16][136] bf16
  __shared__ int s_ids[4][32];

  int tid = threadIdx.x, wv = tid >> 6, lane = tid & 63;
  int r = lane & 15, q = lane >> 4;
  int base = blockIdx.x*64 + wv*16;

  // stage wb: 6 x float4 per thread (coalesced, balanced banks)
  {
    const float4* s2 = (const float4*)(ws + OFF_WB);
    float4* d2 = (float4*)s_wb;
    #pragma unroll
    for (int jj = 0; jj < 6; ++jj){ int i = tid + jj*256; d2[i] = s2[i]; }
  }
  // per-wave ids (wave-local LDS; wave-coherent, no barrier needed)
  if (lane < 32){
    int v;
    if ((base & (T_SEQ-1)) == 0 && lane < 16) v = NVOC;   // pad before sequence start
    else v = ids[base - 16 + lane];
    s_ids[wv][lane] = v;
  }
  // resident head B-frags + LN params + head bias
  short8 HBf[3][4];
  {
    const ushort* hbsrc = (const ushort*)(ws + OFF_HB);
    #pragma unroll
    for (int n2 = 0; n2 < 3; ++n2)
      #pragma unroll
      for (int c = 0; c < 4; ++c)
        HBf[n2][c] = *(const short8*)&hbsrc[((n2*4 + c)*64 + lane)*8];
  }
  float gd[8], bd[8];
  #pragma unroll
  for (int n = 0; n < 8; ++n){ gd[n] = ln_g[n*16 + r]; bd[n] = ln_b[n*16 + r]; }
  float hb[3];
  #pragma unroll
  for (int n2 = 0; n2 < 3; ++n2){ int col = n2*16 + r; hb[n2] = (col < NVOC) ? head_b[col] : 0.f; }

  // zero this wave's T region (400 float4)
  float* T = s_T[wv];
  {
    float4 z; z.x = z.y = z.z = z.w = 0.f;
    float4* t4 = (float4*)T;
    #pragma unroll
    for (int i = 0; i < 7; ++i){ int idx = lane + i*64; if (idx < 400) t4[idx] = z; }
  }
  // build T: tau gathered straight from global (L2-hot), ds_add into wave-local T
  int a = s_ids[wv][16 + r];
  const float* tau_g = ws + OFF_TAU;
  #pragma unroll
  for (int m = 0; m < 4; ++m){
    int w = q*4 + m;
    int c = s_ids[wv][r + 15 - w];
    float tv = tau_g[a*43 + c];
    atomicAdd(&T[r*100 + c], tv);
  }
  if (q == 0) T[r*100 + 43 + a] = 1.0f;          // selects ya row
  __asm__ volatile("s_waitcnt lgkmcnt(0)" ::: "memory");

  // A-frags for msg MFMA (wave-local, before the barrier)
  short8 A1[3];
  #pragma unroll
  for (int ct = 0; ct < 3; ++ct){
    const float4* p = (const float4*)&T[r*100 + ct*32 + q*8];
    float4 u0 = p[0], u1 = p[1];
    short8 v;
    v[0]=f2b(u0.x); v[1]=f2b(u0.y); v[2]=f2b(u0.z); v[3]=f2b(u0.w);
    v[4]=f2b(u1.x); v[5]=f2b(u1.y); v[6]=f2b(u1.z); v[7]=f2b(u1.w);
    A1[ct] = v;
  }
  __syncthreads();                               // wb staged by all waves

  // msg+ya MFMA: y[16 tok x 128 d] = T[16x96] @ W[96x128]
  f32x4 accm[8];
  #pragma unroll
  for (int n = 0; n < 8; ++n){ accm[n][0]=0.f; accm[n][1]=0.f; accm[n][2]=0.f; accm[n][3]=0.f; }
  #pragma unroll
  for (int ct = 0; ct < 3; ++ct){
    #pragma unroll
    for (int n = 0; n < 8; ++n){
      short8 b = *(const short8*)&s_wb[n*1536 + r*96 + ct*32 + q*8];
      accm[n] = __builtin_amdgcn_mfma_f32_16x16x32_bf16(A1[ct], b, accm[n], 0, 0, 0);
    }
  }

  // LN + cyclic scale, write Y bf16 to wave-local LDS (overlay on T)
  ushort* sY = (ushort*)T;                       // Y[16][136] bf16
  #pragma unroll
  for (int reg = 0; reg < 4; ++reg){
    float s1 = 0.f, s2 = 0.f;
    #pragma unroll
    for (int n = 0; n < 8; ++n){ float y = accm[n][reg]; s1 += y; s2 = fmaf(y, y, s2); }
    #pragma unroll
    for (int mk = 1; mk < 16; mk <<= 1){ s1 += __shfl_xor(s1, mk); s2 += __shfl_xor(s2, mk); }
    float mu  = s1 * (1.f/128.f);
    float var = s2 * (1.f/128.f) - mu*mu;
    float rinv = rsqrtf(var + 1e-5f);
    int tok = base + q*4 + reg;
    int m12 = ((tok & (T_SEQ-1)) + 8) % 12;      // (btt + 2048) mod 12
    float sc = fmaf(0.15f, __sinf((float)m12 * 0.52359877559829887f), 1.0f);
    float A_ = rinv * sc;
    #pragma unroll
    for (int n = 0; n < 8; ++n){
      float yl = (accm[n][reg] - mu) * A_;
      float o  = fmaf(yl, gd[n], bd[n]*sc);
      sY[(q*4 + reg)*136 + n*16 + r] = (ushort)f2b(o);
    }
  }

  // head MFMA: out[16 tok x 48] = Y[16x128] @ HW[128x48] (wave-local reads, no barrier)
  f32x4 acch[3];
  #pragma unroll
  for (int n2 = 0; n2 < 3; ++n2){ acch[n2][0]=0.f; acch[n2][1]=0.f; acch[n2][2]=0.f; acch[n2][3]=0.f; }
  short8 A2[4];
  #pragma unroll
  for (int c = 0; c < 4; ++c)
    A2[c] = *(const short8*)&sY[r*136 + c*32 + q*8];
  #pragma unroll
  for (int c = 0; c < 4; ++c){
    #pragma unroll
    for (int n2 = 0; n2 < 3; ++n2)
      acch[n2] = __builtin_amdgcn_mfma_f32_16x16x32_bf16(A2[c], HBf[n2][c], acch[n2], 0, 0, 0);
  }
  #pragma unroll
  for (int n2 = 0; n2 < 3; ++n2){
    int col = n2*16 + r;
    if (col < NVOC){
      #pragma unroll
      for (int reg = 0; reg < 4; ++reg){
        int tok = base + q*4 + reg;
        out[tok*NVOC + col] = acch[n2][reg] + hb[n2];
      }
    }
  }
}

extern "C" void kernel_launch(void* const* d_in, const int* in_sizes, int n_in,
                              void* d_out, int out_size, void* d_ws, size_t ws_size,
                              hipStream_t stream){
  const int*   ids    = (const int*)  d_in[0];
  const float* emb    = (const float*)d_in[1];
  const float* w1     = (const float*)d_in[2];
  const float* b1     = (const float*)d_in[3];
  const float* w2     = (const float*)d_in[4];
  const float* b2     = (const float*)d_in[5];
  const float* wv_w   = (const float*)d_in[6];
  const float* wv_b   = (const float*)d_in[7];
  const float* mg_w   = (const float*)d_in[8];
  const float* mg_b   = (const float*)d_in[9];
  const float* ln_g   = (const float*)d_in[10];
  const float* ln_b   = (const float*)d_in[11];
  const float* head_w = (const float*)d_in[12];
  const float* head_b = (const float*)d_in[13];
  float* ws  = (float*)d_ws;
  float* out = (float*)d_out;
  k_pre <<<dim3(128), dim3(256), 0, stream>>>(emb, w1, b1, w2, b2, wv_w, wv_b,
                                              mg_w, mg_b, head_w, ws);
  k_main<<<dim3(512), dim3(256), 0, stream>>>(ids, ln_g, ln_b, head_b, ws, out);
}

// Round 5
// 30.911 us; speedup vs baseline: 3.9987x; 1.1499x over previous
//
#include <hip/hip_runtime.h>
#include <hip/hip_bf16.h>
#include <math.h>

typedef __attribute__((ext_vector_type(8))) short short8;
typedef __attribute__((ext_vector_type(4))) float f32x4;

#define T_SEQ 2048
#define NVOC 42

// ws float offsets
#define OFF_TAU 0        // 42*43 = 1806 f32
#define OFF_WB  1808     // u16 region: 12288 u16 ([8 n][16 col][96 k] bf16) = 6144 f32 -> 7952
#define OFF_HB  7952     // u16 region: 6144 u16 ([12 frag][64 lane][8] bf16) = 3072 f32 -> 11024

static __device__ __forceinline__ short f2b(float x){
  __hip_bfloat16 h = __float2bfloat16(x);
  return *reinterpret_cast<short*>(&h);
}

// Fused precompute, 128 blocks x 256 threads, block-local deps only.
//  blocks 0..41   : tau row a. w1 register-cached per 16-row chunk (VMEM, coalesced);
//                   emb staged to LDS once, read via uniform ds_read_b128 (broadcast).
//  blocks 42..84  : c -> ve[c] -> vm[c] -> wb bf16 column k=c      (2-way i-split)
//  blocks 85..126 : a -> ya[a] -> wb bf16 column k=43+a            (2-way i-split)
//  block 127      : head_w B-frag pack + zero wb k=85..95
__global__ __launch_bounds__(256) void k_pre(const float* __restrict__ emb,
    const float* __restrict__ w1, const float* __restrict__ b1,
    const float* __restrict__ w2, const float* __restrict__ b2,
    const float* __restrict__ wv_w, const float* __restrict__ wv_b,
    const float* __restrict__ mg_w, const float* __restrict__ mg_b,
    const float* __restrict__ head_w, float* __restrict__ ws){
  __shared__ __align__(16) float sm[5376];
  int blk = blockIdx.x, tid = threadIdx.x;
  ushort* wbu = (ushort*)(ws + OFF_WB);
  if (blk < 42){
    int a = blk;
    // stage all 42 emb rows (5376 f32) to LDS, coalesced
    {
      float4* d4 = (float4*)sm;
      const float4* e4 = (const float4*)emb;
      for (int i = tid; i < 1344; i += 256) d4[i] = e4[i];
    }
    int lane = tid & 63;
    int wvu = __builtin_amdgcn_readfirstlane(tid >> 6);   // wave id, SGPR
    int k = lane;
    float w2k = w2[k];
    float uacc = b1[k];
    float b20 = b2[0];
    __syncthreads();
    float reacc[11];
    #pragma unroll
    for (int cc = 0; cc < 11; ++cc) reacc[cc] = 0.f;
    #pragma unroll 2
    for (int chunk = 0; chunk < 8; ++chunk){
      // 32 independent coalesced w1 loads for this chunk (registers, reused across c)
      float w1u[16], w1r[16];
      #pragma unroll
      for (int j = 0; j < 16; ++j){
        w1u[j] = w1[(chunk*16 + j)*64 + k];
        w1r[j] = w1[(128 + chunk*16 + j)*64 + k];
      }
      // ue accumulation: emb[a] via LDS broadcast
      {
        const float4* ea = (const float4*)(sm + a*128 + chunk*16);
        #pragma unroll
        for (int t = 0; t < 4; ++t){
          float4 e = ea[t];
          uacc = fmaf(e.x, w1u[t*4+0], uacc);
          uacc = fmaf(e.y, w1u[t*4+1], uacc);
          uacc = fmaf(e.z, w1u[t*4+2], uacc);
          uacc = fmaf(e.w, w1u[t*4+3], uacc);
        }
      }
      // re accumulation for this wave's c-set: c = wvu + 4*cc (LDS broadcast reads)
      #pragma unroll
      for (int cc = 0; cc < 11; ++cc){
        int c = wvu + 4*cc;
        if (c < 42){
          const float4* ec = (const float4*)(sm + c*128 + chunk*16);
          #pragma unroll
          for (int t = 0; t < 4; ++t){
            float4 e = ec[t];
            reacc[cc] = fmaf(e.x, w1r[t*4+0], reacc[cc]);
            reacc[cc] = fmaf(e.y, w1r[t*4+1], reacc[cc]);
            reacc[cc] = fmaf(e.z, w1r[t*4+2], reacc[cc]);
            reacc[cc] = fmaf(e.w, w1r[t*4+3], reacc[cc]);
          }
        }
      }
    }
    #pragma unroll
    for (int cc = 0; cc < 11; ++cc){
      int c = wvu + 4*cc;
      if (c < 43){
        float h  = uacc + ((c < 42) ? reacc[cc] : 0.f);
        float sg = 1.f/(1.f + __expf(-h));
        float sl = h * sg * w2k;
        #pragma unroll
        for (int mk = 1; mk < 64; mk <<= 1) sl += __shfl_xor(sl, mk);
        if (lane == 0)
          ws[OFF_TAU + a*43 + c] = 1.f/(1.f + __expf(-(sl + b20)));
      }
    }
  } else if (blk < 85){
    int c = blk - 42;                          // 0..42 (42 == zero-padded neighbor)
    float* s_p0 = sm;                          // [128]
    float* s_p1 = sm + 128;                    // [128]
    float* s_ve = sm + 256;                    // [128]
    int d = tid & 127, h = tid >> 7;
    {
      float acc = (h == 0) ? wv_b[d] : 0.f;
      if (c < 42){
        const float* ec = emb + c*128 + h*64;
        const float* wp = wv_w + (h*64)*128 + d;
        #pragma unroll 8
        for (int i = 0; i < 64; ++i) acc = fmaf(ec[i], wp[i*128], acc);
      }
      (h ? s_p1 : s_p0)[d] = acc;
    }
    __syncthreads();
    if (h == 0) s_ve[d] = s_p0[d] + s_p1[d];
    __syncthreads();
    {
      float acc = 0.f;
      const float* vp = s_ve + h*64;
      const float* mp = mg_w + (128 + h*64)*128 + d;
      #pragma unroll 8
      for (int i = 0; i < 64; ++i) acc = fmaf(vp[i], mp[i*128], acc);
      (h ? s_p1 : s_p0)[d] = acc;
    }
    __syncthreads();
    if (h == 0){
      float vm = s_p0[d] + s_p1[d];
      wbu[(d>>4)*1536 + (d&15)*96 + c] = (ushort)f2b(vm);
    }
  } else if (blk < 127){
    int a = blk - 85;
    float* s_p0 = sm;
    float* s_p1 = sm + 128;
    int d = tid & 127, h = tid >> 7;
    {
      float acc = (h == 0) ? mg_b[d] : 0.f;
      const float* ea = emb + a*128 + h*64;
      const float* mp = mg_w + (h*64)*128 + d;
      #pragma unroll 8
      for (int i = 0; i < 64; ++i) acc = fmaf(ea[i], mp[i*128], acc);
      (h ? s_p1 : s_p0)[d] = acc;
    }
    __syncthreads();
    if (h == 0){
      float ya = s_p0[d] + s_p1[d];
      wbu[(d>>4)*1536 + (d&15)*96 + (43+a)] = (ushort)f2b(ya);
    }
  } else {
    ushort* hbu = (ushort*)(ws + OFF_HB);
    for (int i2 = tid; i2 < 6144; i2 += 256){
      int f = i2 >> 9, ln = (i2 >> 3) & 63, j = i2 & 7;
      int n2 = f >> 2, cc = f & 3;
      int kk = cc*32 + (ln>>4)*8 + j;
      int col = n2*16 + (ln & 15);
      float v = (col < NVOC) ? head_w[kk*NVOC + col] : 0.f;
      hbu[i2] = (ushort)f2b(v);
    }
    for (int i = tid; i < 1408; i += 256){
      int n = i/176, rem = i%176, col = rem/11, kk = 85 + rem%11;
      wbu[n*1536 + col*96 + kk] = 0;
    }
  }
}

// Main: per wave 16 tokens. wb staged to LDS; tau gathered from global per-lane;
// T built wave-locally (overlaps staging); ONE barrier; 2 MFMA stages.
__global__ __launch_bounds__(256) void k_main(const int* __restrict__ ids,
    const float* __restrict__ ln_g, const float* __restrict__ ln_b,
    const float* __restrict__ head_b, const float* __restrict__ ws,
    float* __restrict__ out){
  __shared__ __align__(16) ushort s_wb[12288];
  __shared__ __align__(16) float  s_T[4][1600];   // per-wave: T[16][100] f32, later Y[16][136] bf16
  __shared__ int s_ids[4][32];

  int tid = threadIdx.x, wv = tid >> 6, lane = tid & 63;
  int r = lane & 15, q = lane >> 4;
  int base = blockIdx.x*64 + wv*16;

  // stage wb: 6 x float4 per thread (coalesced, balanced banks)
  {
    const float4* s2 = (const float4*)(ws + OFF_WB);
    float4* d2 = (float4*)s_wb;
    #pragma unroll
    for (int jj = 0; jj < 6; ++jj){ int i = tid + jj*256; d2[i] = s2[i]; }
  }
  // per-wave ids (wave-local LDS; wave-coherent, no barrier needed)
  if (lane < 32){
    int v;
    if ((base & (T_SEQ-1)) == 0 && lane < 16) v = NVOC;   // pad before sequence start
    else v = ids[base - 16 + lane];
    s_ids[wv][lane] = v;
  }
  // resident head B-frags + LN params + head bias
  short8 HBf[3][4];
  {
    const ushort* hbsrc = (const ushort*)(ws + OFF_HB);
    #pragma unroll
    for (int n2 = 0; n2 < 3; ++n2)
      #pragma unroll
      for (int c = 0; c < 4; ++c)
        HBf[n2][c] = *(const short8*)&hbsrc[((n2*4 + c)*64 + lane)*8];
  }
  float gd[8], bd[8];
  #pragma unroll
  for (int n = 0; n < 8; ++n){ gd[n] = ln_g[n*16 + r]; bd[n] = ln_b[n*16 + r]; }
  float hb[3];
  #pragma unroll
  for (int n2 = 0; n2 < 3; ++n2){ int col = n2*16 + r; hb[n2] = (col < NVOC) ? head_b[col] : 0.f; }

  // zero this wave's T region (400 float4)
  float* T = s_T[wv];
  {
    float4 z; z.x = z.y = z.z = z.w = 0.f;
    float4* t4 = (float4*)T;
    #pragma unroll
    for (int i = 0; i < 7; ++i){ int idx = lane + i*64; if (idx < 400) t4[idx] = z; }
  }
  // build T: tau gathered straight from global (L2-hot), ds_add into wave-local T
  int a = s_ids[wv][16 + r];
  const float* tau_g = ws + OFF_TAU;
  #pragma unroll
  for (int m = 0; m < 4; ++m){
    int w = q*4 + m;
    int c = s_ids[wv][r + 15 - w];
    float tv = tau_g[a*43 + c];
    atomicAdd(&T[r*100 + c], tv);
  }
  if (q == 0) T[r*100 + 43 + a] = 1.0f;          // selects ya row
  __asm__ volatile("s_waitcnt lgkmcnt(0)" ::: "memory");

  // A-frags for msg MFMA (wave-local, before the barrier)
  short8 A1[3];
  #pragma unroll
  for (int ct = 0; ct < 3; ++ct){
    const float4* p = (const float4*)&T[r*100 + ct*32 + q*8];
    float4 u0 = p[0], u1 = p[1];
    short8 v;
    v[0]=f2b(u0.x); v[1]=f2b(u0.y); v[2]=f2b(u0.z); v[3]=f2b(u0.w);
    v[4]=f2b(u1.x); v[5]=f2b(u1.y); v[6]=f2b(u1.z); v[7]=f2b(u1.w);
    A1[ct] = v;
  }
  __syncthreads();                               // wb staged by all waves

  // msg+ya MFMA: y[16 tok x 128 d] = T[16x96] @ W[96x128]
  f32x4 accm[8];
  #pragma unroll
  for (int n = 0; n < 8; ++n){ accm[n][0]=0.f; accm[n][1]=0.f; accm[n][2]=0.f; accm[n][3]=0.f; }
  #pragma unroll
  for (int ct = 0; ct < 3; ++ct){
    #pragma unroll
    for (int n = 0; n < 8; ++n){
      short8 b = *(const short8*)&s_wb[n*1536 + r*96 + ct*32 + q*8];
      accm[n] = __builtin_amdgcn_mfma_f32_16x16x32_bf16(A1[ct], b, accm[n], 0, 0, 0);
    }
  }

  // LN + cyclic scale, write Y bf16 to wave-local LDS (overlay on T)
  ushort* sY = (ushort*)T;                       // Y[16][136] bf16
  #pragma unroll
  for (int reg = 0; reg < 4; ++reg){
    float s1 = 0.f, s2 = 0.f;
    #pragma unroll
    for (int n = 0; n < 8; ++n){ float y = accm[n][reg]; s1 += y; s2 = fmaf(y, y, s2); }
    #pragma unroll
    for (int mk = 1; mk < 16; mk <<= 1){ s1 += __shfl_xor(s1, mk); s2 += __shfl_xor(s2, mk); }
    float mu  = s1 * (1.f/128.f);
    float var = s2 * (1.f/128.f) - mu*mu;
    float rinv = rsqrtf(var + 1e-5f);
    int tok = base + q*4 + reg;
    int m12 = ((tok & (T_SEQ-1)) + 8) % 12;      // (btt + 2048) mod 12
    float sc = fmaf(0.15f, __sinf((float)m12 * 0.52359877559829887f), 1.0f);
    float A_ = rinv * sc;
    #pragma unroll
    for (int n = 0; n < 8; ++n){
      float yl = (accm[n][reg] - mu) * A_;
      float o  = fmaf(yl, gd[n], bd[n]*sc);
      sY[(q*4 + reg)*136 + n*16 + r] = (ushort)f2b(o);
    }
  }

  // head MFMA: out[16 tok x 48] = Y[16x128] @ HW[128x48] (wave-local reads, no barrier)
  f32x4 acch[3];
  #pragma unroll
  for (int n2 = 0; n2 < 3; ++n2){ acch[n2][0]=0.f; acch[n2][1]=0.f; acch[n2][2]=0.f; acch[n2][3]=0.f; }
  short8 A2[4];
  #pragma unroll
  for (int c = 0; c < 4; ++c)
    A2[c] = *(const short8*)&sY[r*136 + c*32 + q*8];
  #pragma unroll
  for (int c = 0; c < 4; ++c){
    #pragma unroll
    for (int n2 = 0; n2 < 3; ++n2)
      acch[n2] = __builtin_amdgcn_mfma_f32_16x16x32_bf16(A2[c], HBf[n2][c], acch[n2], 0, 0, 0);
  }
  #pragma unroll
  for (int n2 = 0; n2 < 3; ++n2){
    int col = n2*16 + r;
    if (col < NVOC){
      #pragma unroll
      for (int reg = 0; reg < 4; ++reg){
        int tok = base + q*4 + reg;
        out[tok*NVOC + col] = acch[n2][reg] + hb[n2];
      }
    }
  }
}

extern "C" void kernel_launch(void* const* d_in, const int* in_sizes, int n_in,
                              void* d_out, int out_size, void* d_ws, size_t ws_size,
                              hipStream_t stream){
  const int*   ids    = (const int*)  d_in[0];
  const float* emb    = (const float*)d_in[1];
  const float* w1     = (const float*)d_in[2];
  const float* b1     = (const float*)d_in[3];
  const float* w2     = (const float*)d_in[4];
  const float* b2     = (const float*)d_in[5];
  const float* wv_w   = (const float*)d_in[6];
  const float* wv_b   = (const float*)d_in[7];
  const float* mg_w   = (const float*)d_in[8];
  const float* mg_b   = (const float*)d_in[9];
  const float* ln_g   = (const float*)d_in[10];
  const float* ln_b   = (const float*)d_in[11];
  const float* head_w = (const float*)d_in[12];
  const float* head_b = (const float*)d_in[13];
  float* ws  = (float*)d_ws;
  float* out = (float*)d_out;
  k_pre <<<dim3(128), dim3(256), 0, stream>>>(emb, w1, b1, w2, b2, wv_w, wv_b,
                                              mg_w, mg_b, head_w, ws);
  k_main<<<dim3(512), dim3(256), 0, stream>>>(ids, ln_g, ln_b, head_b, ws, out);
}